// Round 12
// baseline (36.359 us; speedup 1.0000x reference)
//
#include <hip/hip_runtime.h>
#include <math.h>

#define NB 16
#define NA 19200
#define NT 50
#define NC 80
#define LAMBDA_COORD 5.0f
#define F_EPS 1e-6f

// Node A: block = (image, target-group of TPG, anchor-half). 320 blocks -> all CUs.
#define TPG 5
#define NGRP (NT / TPG)          // 10
#define NHALF 2
#define HALF_A (NA / NHALF)      // 9600
#define KA_BLOCKS (NB * NGRP * NHALF)   // 320
#define KA_THREADS 1024
#define KA_WAVES (KA_THREADS / 64)
#define OBJ_F4_PER_BLK (NB * NA / 4 / KA_BLOCKS)   // 240 float4s of pc per block

#define W_OBJ (1.0f / (float)(NB * NA))
#define W_BOX (LAMBDA_COORD / (float)(NB * NT))
#define W_CLS (1.0f / (float)(NB * NT * NC))

// ws layout:
// [0     .. 1280)   float part[320]
// [2048  .. 8448)   float val_part[NB*NT*2]
// [8448  .. 14848)  int   idx_part[NB*NT*2]

__device__ __forceinline__ float bce0(float x) {   // bce_logits(x, 0)
    return fmaxf(x, 0.0f) + log1pf(expf(-fabsf(x)));
}

// ---- Node A: half-anchor argmax (rcp + depth-3 prefetch) + bulk obj slice ----
__global__ __launch_bounds__(1024) void kA(
        const float* __restrict__ pb,
        const float* __restrict__ pc,
        const float* __restrict__ tb,
        float* __restrict__ val_part,
        int* __restrict__ idx_part,
        float* __restrict__ part,
        float* __restrict__ out) {
    const float4* pb4 = (const float4*)pb;
    const float4* tb4 = (const float4*)tb;
    const float4* pc4 = (const float4*)pc;

    const int blk = blockIdx.x;
    const int b   = blk / (NGRP * NHALF);
    const int r   = blk % (NGRP * NHALF);
    const int g   = r / NHALF;
    const int h   = r % NHALF;
    const int tid = threadIdx.x;
    const int wave = tid >> 6;
    const int lane = tid & 63;

    if (blk == 0 && tid == 0) out[0] = 0.0f;   // kB atomicAdds after node boundary

    float4 t4[TPG];
    float  ta[TPG];
    #pragma unroll
    for (int i = 0; i < TPG; ++i) {
        t4[i] = tb4[b * NT + g * TPG + i];
        ta[i] = (t4[i].z - t4[i].x) * (t4[i].w - t4[i].y) + F_EPS;  // fold EPS
    }

    float best[TPG];
    int   bidx[TPG];
    #pragma unroll
    for (int i = 0; i < TPG; ++i) { best[i] = -1.0f; bidx[i] = NA; }

    // ---- depth-3 software-pipelined scan of this half's anchors ----
    const size_t boff = (size_t)b * NA + h * HALF_A;
    int a0 = tid;
    float4 p0 = pb4[boff + a0];
    int a1 = a0 + KA_THREADS;
    bool v1 = a1 < HALF_A;
    float4 p1;
    if (v1) p1 = pb4[boff + a1];
    int a2 = a1 + KA_THREADS;
    bool v2 = v1 && (a2 < HALF_A);
    float4 p2;
    if (v2) p2 = pb4[boff + a2];

    while (true) {
        const int a3 = a2 + KA_THREADS;
        const bool v3 = v2 && (a3 < HALF_A);
        float4 p3;
        if (v3) p3 = pb4[boff + a3];

        {   // compute on p0/a0 (ascending -> first-idx ties kept)
            float area1 = (p0.z - p0.x) * (p0.w - p0.y);
            const int gidx = h * HALF_A + a0;
            #pragma unroll
            for (int i = 0; i < TPG; ++i) {
                float ix1 = fmaxf(p0.x, t4[i].x), iy1 = fmaxf(p0.y, t4[i].y);
                float ix2 = fminf(p0.z, t4[i].z), iy2 = fminf(p0.w, t4[i].w);
                float inter = fmaxf(ix2 - ix1, 0.0f) * fmaxf(iy2 - iy1, 0.0f);
                float u = area1 + ta[i] - inter;
                float iou = inter * __builtin_amdgcn_rcpf(u);
                if (iou > best[i]) { best[i] = iou; bidx[i] = gidx; }
            }
        }

        if (!v1) break;
        p0 = p1; a0 = a1;
        p1 = p2; a1 = a2; v1 = v2;
        p2 = p3; a2 = a3; v2 = v3;
    }

    __shared__ float swv[KA_WAVES][TPG];
    __shared__ int   swi[KA_WAVES][TPG];
    __shared__ float swred[KA_WAVES];

    #pragma unroll
    for (int i = 0; i < TPG; ++i) {
        float v = best[i];
        int   ix = bidx[i];
        #pragma unroll
        for (int m = 1; m < 64; m <<= 1) {
            float ov = __shfl_xor(v, m);
            int   oi = __shfl_xor(ix, m);
            if (ov > v || (ov == v && oi < ix)) { v = ov; ix = oi; }
        }
        if (lane == 0) { swv[wave][i] = v; swi[wave][i] = ix; }
    }
    __syncthreads();

    if (tid < TPG) {
        float v = swv[0][tid];
        int   ix = swi[0][tid];
        #pragma unroll
        for (int w = 1; w < KA_WAVES; ++w) {
            float ov = swv[w][tid];
            int   oi = swi[w][tid];
            if (ov > v || (ov == v && oi < ix)) { v = ov; ix = oi; }
        }
        const int t = b * NT + g * TPG + tid;
        val_part[t * 2 + h] = v;
        idx_part[t * 2 + h] = ix;
    }

    // ---- bulk objectness: this block's 240-float4 slice of pc ----
    float s = 0.0f;
    if (tid < OBJ_F4_PER_BLK) {
        float4 v4 = pc4[blk * OBJ_F4_PER_BLK + tid];
        s = W_OBJ * (bce0(v4.x) + bce0(v4.y) + bce0(v4.z) + bce0(v4.w));
    }
    #pragma unroll
    for (int m = 32; m > 0; m >>= 1) s += __shfl_down(s, m);
    if (lane == 0) swred[wave] = s;
    __syncthreads();
    if (tid < KA_WAVES) {
        float v = swred[tid];
        #pragma unroll
        for (int m = 8; m > 0; m >>= 1) v += __shfl_down(v, m);
        if (tid == 0) part[blk] = v;
    }
}

// ---- Node B: one block per image. Merge halves, cls BCE, CIoU, obj correction. ----
__global__ __launch_bounds__(256) void kB(
        const float* __restrict__ pb,
        const float* __restrict__ pc,
        const float* __restrict__ pcls,
        const float* __restrict__ tb,
        const int* __restrict__ tl,
        const float* __restrict__ val_part,
        const int* __restrict__ idx_part,
        const float* __restrict__ part,
        float* __restrict__ out) {
    const int b   = blockIdx.x;
    const int tid = threadIdx.x;
    const int wave = tid >> 6;
    const int lane = tid & 63;

    __shared__ int   sbi[NT];
    __shared__ int   slab[NT];
    __shared__ float swred[4];

    // merge the two half-partials per target (half0 idx < half1 idx; tie -> min)
    if (tid < NT) {
        const int t = b * NT + tid;
        float v0 = val_part[t * 2 + 0]; int i0 = idx_part[t * 2 + 0];
        float v1 = val_part[t * 2 + 1]; int i1 = idx_part[t * 2 + 1];
        sbi[tid]  = (v1 > v0 || (v1 == v0 && i1 < i0)) ? i1 : i0;
        slab[tid] = tl[b * NT + tid];
    }
    __syncthreads();

    float s = 0.0f;

    // this image's slice of the 320 obj/bulk partials (20 per image)
    if (tid < NGRP * NHALF) s += part[b * NGRP * NHALF + tid];

    // class BCE: 50*80 = 4000 elems, bce(x,z) = bce0(x) - x*z
    for (int i = tid; i < NT * NC; i += 256) {
        const int t = i / NC;
        const int c = i - t * NC;
        float x = pcls[((size_t)b * NA + sbi[t]) * NC + c];
        s += W_CLS * (bce0(x) - (slab[t] == c ? x : 0.0f));
    }

    if (tid < NT) {
        const int bi = sbi[tid];

        // obj correction: bce(x,1)-bce(x,0) = -x, once per UNIQUE best anchor
        bool dup = false;
        for (int tp = 0; tp < tid; ++tp)
            if (sbi[tp] == bi) dup = true;
        if (!dup) s -= W_OBJ * pc[(size_t)b * NA + bi];

        // CIoU (exact reference formula)
        const float* p  = pb + ((size_t)b * NA + bi) * 4;
        const float* tg = tb + ((size_t)b * NT + tid) * 4;
        float b1x1 = p[0],  b1y1 = p[1],  b1x2 = p[2],  b1y2 = p[3];
        float b2x1 = tg[0], b2y1 = tg[1], b2x2 = tg[2], b2y2 = tg[3];

        float area1 = (b1x2 - b1x1) * (b1y2 - b1y1);
        float area2 = (b2x2 - b2x1) * (b2y2 - b2y1);
        float iw = fmaxf(fminf(b1x2, b2x2) - fmaxf(b1x1, b2x1), 0.0f);
        float ih = fmaxf(fminf(b1y2, b2y2) - fmaxf(b1y1, b2y1), 0.0f);
        float inter = iw * ih;
        float iou = inter / (area1 + area2 - inter + F_EPS);

        float cdx = fmaxf(b1x2, b2x2) - fminf(b1x1, b2x1);
        float cdy = fmaxf(b1y2, b2y2) - fminf(b1y1, b2y1);
        float c_diag = cdx * cdx + cdy * cdy;

        float cx = (b1x1 + b1x2 - b2x1 - b2x2) * 0.5f;
        float cy = (b1y1 + b1y2 - b2y1 - b2y2) * 0.5f;
        float center_dist = cx * cx + cy * cy;

        float w1 = b1x2 - b1x1, h1 = b1y2 - b1y1;
        float w2 = b2x2 - b2x1, h2 = b2y2 - b2y1;
        float dat = atanf(w2 / h2) - atanf(w1 / h1);
        float vv = (float)(4.0 / (M_PI * M_PI)) * dat * dat;
        float alpha = vv / (1.0f - iou + vv + F_EPS);
        float ciou = iou - center_dist / c_diag - alpha * vv;
        s += W_BOX * (1.0f - ciou);
    }

    // block reduce -> one atomicAdd per image (16 total, contention-free)
    #pragma unroll
    for (int m = 32; m > 0; m >>= 1) s += __shfl_down(s, m);
    if (lane == 0) swred[wave] = s;
    __syncthreads();
    if (tid == 0) atomicAdd(out, swred[0] + swred[1] + swred[2] + swred[3]);
}

extern "C" void kernel_launch(void* const* d_in, const int* in_sizes, int n_in,
                              void* d_out, int out_size, void* d_ws, size_t ws_size,
                              hipStream_t stream) {
    const float* pb   = (const float*)d_in[0];   // (B,A,4)
    const float* pc   = (const float*)d_in[1];   // (B,A,1)
    const float* pcls = (const float*)d_in[2];   // (B,A,C)
    const float* tb   = (const float*)d_in[3];   // (B,T,4)
    const int*   tl   = (const int*)d_in[4];     // (B,T)

    char* ws = (char*)d_ws;
    float* part     = (float*)ws;                 // 320 floats
    float* val_part = (float*)(ws + 2048);        // 1600 floats
    int*   idx_part = (int*)(ws + 8448);          // 1600 ints

    kA<<<KA_BLOCKS, KA_THREADS, 0, stream>>>(
        pb, pc, tb, val_part, idx_part, part, (float*)d_out);
    kB<<<NB, 256, 0, stream>>>(
        pb, pc, pcls, tb, tl, val_part, idx_part, part, (float*)d_out);
}

// Round 13
// 35.634 us; speedup vs baseline: 1.0203x; 1.0203x over previous
//
#include <hip/hip_runtime.h>
#include <math.h>

#define NB 16
#define NA 19200
#define NT 50
#define NC 80
#define LAMBDA_COORD 5.0f
#define F_EPS 1e-6f

// Node A: block = (image, group of TPG targets). Full-anchor scan per block. (r11 structure)
#define TPG 5
#define NGRP (NT / TPG)          // 10
#define KA_BLOCKS (NB * NGRP)    // 160
#define KA_THREADS 1024
#define KA_WAVES (KA_THREADS / 64)
#define OBJ_F4_PER_BLK (NB * NA / 4 / KA_BLOCKS)   // 480 float4s of pc per block

#define W_OBJ (1.0f / (float)(NB * NA))
#define W_BOX (LAMBDA_COORD / (float)(NB * NT))
#define W_CLS (1.0f / (float)(NB * NT * NC))

// ws layout: [0..1024) float part[160]; [1024..4224) int best_idx[800]

__device__ __forceinline__ float bce0(float x) {   // bce_logits(x, 0)
    return fmaxf(x, 0.0f) + log1pf(expf(-fabsf(x)));
}

// ---- Node A: argmax (cross-mult compare, div/rcp-free) + CIoU + cls BCE + obj slice ----
__global__ __launch_bounds__(1024) void kA(
        const float* __restrict__ pb,
        const float* __restrict__ pc,
        const float* __restrict__ pcls,
        const float* __restrict__ tb,
        const int* __restrict__ tl,
        int* __restrict__ best_idx,
        float* __restrict__ part) {
    const float4* pb4 = (const float4*)pb;
    const float4* tb4 = (const float4*)tb;
    const float4* pc4 = (const float4*)pc;

    const int b   = blockIdx.x / NGRP;
    const int g   = blockIdx.x % NGRP;
    const int tid = threadIdx.x;
    const int wave = tid >> 6;
    const int lane = tid & 63;

    float4 t4[TPG];
    float  ta[TPG];
    #pragma unroll
    for (int i = 0; i < TPG; ++i) {
        t4[i] = tb4[b * NT + g * TPG + i];
        ta[i] = (t4[i].z - t4[i].x) * (t4[i].w - t4[i].y) + F_EPS;  // fold EPS into union
    }

    // per-target best as (inter, union) pair -> no division in the scan
    float bI[TPG], bU[TPG];
    int   bidx[TPG];
    #pragma unroll
    for (int i = 0; i < TPG; ++i) { bI[i] = -1.0f; bU[i] = 1.0f; bidx[i] = NA; }

    // ---- depth-2 software-pipelined scan (ascending a -> first-idx ties kept) ----
    const size_t boff = (size_t)b * NA;
    int a0 = tid;
    float4 p0 = pb4[boff + a0];
    int a1 = a0 + KA_THREADS;
    bool h1 = a1 < NA;
    float4 p1;
    if (h1) p1 = pb4[boff + a1];

    while (true) {
        const int a2 = a1 + KA_THREADS;
        const bool h2 = h1 && (a2 < NA);
        float4 p2;
        if (h2) p2 = pb4[boff + a2];

        {   // compute on p0/a0
            float area1 = (p0.z - p0.x) * (p0.w - p0.y);
            #pragma unroll
            for (int i = 0; i < TPG; ++i) {
                float ix1 = fmaxf(p0.x, t4[i].x), iy1 = fmaxf(p0.y, t4[i].y);
                float ix2 = fminf(p0.z, t4[i].z), iy2 = fminf(p0.w, t4[i].w);
                float inter = fmaxf(ix2 - ix1, 0.0f) * fmaxf(iy2 - iy1, 0.0f);
                float u = area1 + ta[i] - inter;           // union + EPS (>0)
                // iou_new > iou_best  <=>  inter*bU > bI*u   (u, bU > 0)
                if (inter * bU[i] > bI[i] * u) { bI[i] = inter; bU[i] = u; bidx[i] = a0; }
            }
        }

        if (!h1) break;
        p0 = p1; a0 = a1;
        p1 = p2; a1 = a2; h1 = h2;
    }

    __shared__ float swvI[KA_WAVES][TPG];
    __shared__ float swvU[KA_WAVES][TPG];
    __shared__ int   swi[KA_WAVES][TPG];
    __shared__ int   sbi5[TPG];
    __shared__ float swred[KA_WAVES];

    // wave butterfly: max ratio via cross-mult, tie -> min idx
    #pragma unroll
    for (int i = 0; i < TPG; ++i) {
        float vI = bI[i], vU = bU[i];
        int   ix = bidx[i];
        #pragma unroll
        for (int m = 1; m < 64; m <<= 1) {
            float oI = __shfl_xor(vI, m);
            float oU = __shfl_xor(vU, m);
            int   oi = __shfl_xor(ix, m);
            float lhs = oI * vU, rhs = vI * oU;
            if (lhs > rhs || (lhs == rhs && oi < ix)) { vI = oI; vU = oU; ix = oi; }
        }
        if (lane == 0) { swvI[wave][i] = vI; swvU[wave][i] = vU; swi[wave][i] = ix; }
    }
    __syncthreads();

    if (tid < TPG) {
        float vI = swvI[0][tid], vU = swvU[0][tid];
        int   ix = swi[0][tid];
        #pragma unroll
        for (int w = 1; w < KA_WAVES; ++w) {
            float oI = swvI[w][tid], oU = swvU[w][tid];
            int   oi = swi[w][tid];
            float lhs = oI * vU, rhs = vI * oU;
            if (lhs > rhs || (lhs == rhs && oi < ix)) { vI = oI; vU = oU; ix = oi; }
        }
        best_idx[b * NT + g * TPG + tid] = ix;
        sbi5[tid] = ix;
    }
    __syncthreads();

    // ---------- epilogue: weighted per-thread accumulator ----------
    float s = 0.0f;

    // cls BCE for this block's 5 targets: threads 0..399, one (t,c) each
    if (tid < TPG * NC) {
        const int t = tid / NC;
        const int c = tid - t * NC;
        float x = pcls[((size_t)b * NA + sbi5[t]) * NC + c];
        int lab = tl[b * NT + g * TPG + t];
        s += W_CLS * (bce0(x) - (lab == c ? x : 0.0f));
    }

    // CIoU for this block's 5 targets (threads 512..516, exact reference formula)
    if (tid >= 512 && tid < 512 + TPG) {
        const int t  = tid - 512;
        const int bi = sbi5[t];
        const float* p  = pb + ((size_t)b * NA + bi) * 4;
        const float* tg = tb + ((size_t)b * NT + g * TPG + t) * 4;
        float b1x1 = p[0],  b1y1 = p[1],  b1x2 = p[2],  b1y2 = p[3];
        float b2x1 = tg[0], b2y1 = tg[1], b2x2 = tg[2], b2y2 = tg[3];

        float area1 = (b1x2 - b1x1) * (b1y2 - b1y1);
        float area2 = (b2x2 - b2x1) * (b2y2 - b2y1);
        float iw = fmaxf(fminf(b1x2, b2x2) - fmaxf(b1x1, b2x1), 0.0f);
        float ih = fmaxf(fminf(b1y2, b2y2) - fmaxf(b1y1, b2y1), 0.0f);
        float inter = iw * ih;
        float iou = inter / (area1 + area2 - inter + F_EPS);

        float cdx = fmaxf(b1x2, b2x2) - fminf(b1x1, b2x1);
        float cdy = fmaxf(b1y2, b2y2) - fminf(b1y1, b2y1);
        float c_diag = cdx * cdx + cdy * cdy;

        float cx = (b1x1 + b1x2 - b2x1 - b2x2) * 0.5f;
        float cy = (b1y1 + b1y2 - b2y1 - b2y2) * 0.5f;
        float center_dist = cx * cx + cy * cy;

        float w1 = b1x2 - b1x1, h1 = b1y2 - b1y1;
        float w2 = b2x2 - b2x1, h2 = b2y2 - b2y1;
        float dat = atanf(w2 / h2) - atanf(w1 / h1);
        float vv = (float)(4.0 / (M_PI * M_PI)) * dat * dat;
        float alpha = vv / (1.0f - iou + vv + F_EPS);
        float ciou = iou - center_dist / c_diag - alpha * vv;
        s += W_BOX * (1.0f - ciou);
    }

    // bulk objectness: this block's 480-float4 slice of pc (no mask needed)
    if (tid < OBJ_F4_PER_BLK) {
        float4 v4 = pc4[blockIdx.x * OBJ_F4_PER_BLK + tid];
        s += W_OBJ * (bce0(v4.x) + bce0(v4.y) + bce0(v4.z) + bce0(v4.w));
    }

    // block reduce -> part[blockIdx.x]
    #pragma unroll
    for (int m = 32; m > 0; m >>= 1) s += __shfl_down(s, m);
    if (lane == 0) swred[wave] = s;
    __syncthreads();
    if (tid < KA_WAVES) {
        float v = swred[tid];
        #pragma unroll
        for (int m = 8; m > 0; m >>= 1) v += __shfl_down(v, m);
        if (tid == 0) part[blockIdx.x] = v;
    }
}

// ---- Node B: sum partials + dedup'd objectness correction (1 block) ----
__global__ __launch_bounds__(256) void kB(
        const float* __restrict__ pc,
        const int* __restrict__ best_idx,
        const float* __restrict__ part,
        float* __restrict__ out) {
    const int tid = threadIdx.x;
    const int wave = tid >> 6;
    const int lane = tid & 63;

    __shared__ int   sbi[NB * NT];
    __shared__ float swred[4];

    for (int i = tid; i < NB * NT; i += 256) sbi[i] = best_idx[i];
    __syncthreads();

    float s = 0.0f;
    if (tid < KA_BLOCKS) s += part[tid];

    // obj correction: bce(x,1)-bce(x,0) = -x, once per UNIQUE best anchor per image
    for (int i = tid; i < NB * NT; i += 256) {
        const int b = i / NT;
        const int t = i - b * NT;
        const int bi = sbi[i];
        bool dup = false;
        for (int tp = 0; tp < t; ++tp)
            if (sbi[b * NT + tp] == bi) dup = true;
        if (!dup) s -= W_OBJ * pc[(size_t)b * NA + bi];
    }

    #pragma unroll
    for (int m = 32; m > 0; m >>= 1) s += __shfl_down(s, m);
    if (lane == 0) swred[wave] = s;
    __syncthreads();
    if (tid == 0) out[0] = swred[0] + swred[1] + swred[2] + swred[3];
}

extern "C" void kernel_launch(void* const* d_in, const int* in_sizes, int n_in,
                              void* d_out, int out_size, void* d_ws, size_t ws_size,
                              hipStream_t stream) {
    const float* pb   = (const float*)d_in[0];   // (B,A,4)
    const float* pc   = (const float*)d_in[1];   // (B,A,1)
    const float* pcls = (const float*)d_in[2];   // (B,A,C)
    const float* tb   = (const float*)d_in[3];   // (B,T,4)
    const int*   tl   = (const int*)d_in[4];     // (B,T)

    char* ws = (char*)d_ws;
    float* part     = (float*)ws;             // 160 floats
    int*   best_idx = (int*)(ws + 1024);      // 800 ints

    kA<<<KA_BLOCKS, KA_THREADS, 0, stream>>>(pb, pc, pcls, tb, tl, best_idx, part);
    kB<<<1, 256, 0, stream>>>(pc, best_idx, part, (float*)d_out);
}

// Round 14
// 35.045 us; speedup vs baseline: 1.0375x; 1.0168x over previous
//
#include <hip/hip_runtime.h>
#include <math.h>

#define NB 16
#define NA 19200
#define NT 50
#define NC 80
#define LAMBDA_COORD 5.0f
#define F_EPS 1e-6f

// Node A: block = (image, group of TPG targets). Full-anchor scan per block.
#define TPG 5
#define NGRP (NT / TPG)          // 10
#define KA_BLOCKS (NB * NGRP)    // 160
#define KA_THREADS 1024
#define KA_WAVES (KA_THREADS / 64)
#define OBJ_F4_PER_BLK (NB * NA / 4 / KA_BLOCKS)   // 480 float4s of pc per block

#define W_OBJ (1.0f / (float)(NB * NA))
#define W_BOX (LAMBDA_COORD / (float)(NB * NT))
#define W_CLS (1.0f / (float)(NB * NT * NC))

// ws layout: [0..1024) float part[160]; [1024..4224) int best_idx[800]

__device__ __forceinline__ float bce0(float x) {   // bce_logits(x, 0)
    return fmaxf(x, 0.0f) + log1pf(expf(-fabsf(x)));
}

// ---- Node A: argmax (fast-rcp + depth-2 prefetch) + CIoU + cls BCE + obj slice ----
__global__ __launch_bounds__(1024) void kA(
        const float* __restrict__ pb,
        const float* __restrict__ pc,
        const float* __restrict__ pcls,
        const float* __restrict__ tb,
        const int* __restrict__ tl,
        int* __restrict__ best_idx,
        float* __restrict__ part) {
    const float4* pb4 = (const float4*)pb;
    const float4* tb4 = (const float4*)tb;
    const float4* pc4 = (const float4*)pc;

    const int b   = blockIdx.x / NGRP;
    const int g   = blockIdx.x % NGRP;
    const int tid = threadIdx.x;
    const int wave = tid >> 6;
    const int lane = tid & 63;

    float4 t4[TPG];
    float  ta[TPG];
    #pragma unroll
    for (int i = 0; i < TPG; ++i) {
        t4[i] = tb4[b * NT + g * TPG + i];
        ta[i] = (t4[i].z - t4[i].x) * (t4[i].w - t4[i].y) + F_EPS;  // fold EPS
    }

    float best[TPG];
    int   bidx[TPG];
    #pragma unroll
    for (int i = 0; i < TPG; ++i) { best[i] = -1.0f; bidx[i] = NA; }

    // ---- depth-2 software-pipelined scan (ascending a -> first-idx ties kept) ----
    const size_t boff = (size_t)b * NA;
    int a0 = tid;
    float4 p0 = pb4[boff + a0];
    int a1 = a0 + KA_THREADS;
    bool h1 = a1 < NA;
    float4 p1;
    if (h1) p1 = pb4[boff + a1];

    while (true) {
        const int a2 = a1 + KA_THREADS;
        const bool h2 = h1 && (a2 < NA);
        float4 p2;
        if (h2) p2 = pb4[boff + a2];

        // compute on p0 / a0
        {
            float area1 = (p0.z - p0.x) * (p0.w - p0.y);
            #pragma unroll
            for (int i = 0; i < TPG; ++i) {
                float ix1 = fmaxf(p0.x, t4[i].x), iy1 = fmaxf(p0.y, t4[i].y);
                float ix2 = fminf(p0.z, t4[i].z), iy2 = fminf(p0.w, t4[i].w);
                float inter = fmaxf(ix2 - ix1, 0.0f) * fmaxf(iy2 - iy1, 0.0f);
                float u = area1 + ta[i] - inter;          // union + EPS (EPS folded in ta)
                float iou = inter * __builtin_amdgcn_rcpf(u);
                if (iou > best[i]) { best[i] = iou; bidx[i] = a0; }
            }
        }

        if (!h1) break;
        p0 = p1; a0 = a1;
        p1 = p2; a1 = a2; h1 = h2;
    }

    __shared__ float swv[KA_WAVES][TPG];
    __shared__ int   swi[KA_WAVES][TPG];
    __shared__ int   sbi5[TPG];
    __shared__ float swred[KA_WAVES];

    #pragma unroll
    for (int i = 0; i < TPG; ++i) {
        float v = best[i];
        int   ix = bidx[i];
        #pragma unroll
        for (int m = 1; m < 64; m <<= 1) {
            float ov = __shfl_xor(v, m);
            int   oi = __shfl_xor(ix, m);
            if (ov > v || (ov == v && oi < ix)) { v = ov; ix = oi; }
        }
        if (lane == 0) { swv[wave][i] = v; swi[wave][i] = ix; }
    }
    __syncthreads();

    if (tid < TPG) {
        float v = swv[0][tid];
        int   ix = swi[0][tid];
        #pragma unroll
        for (int w = 1; w < KA_WAVES; ++w) {
            float ov = swv[w][tid];
            int   oi = swi[w][tid];
            if (ov > v || (ov == v && oi < ix)) { v = ov; ix = oi; }
        }
        best_idx[b * NT + g * TPG + tid] = ix;
        sbi5[tid] = ix;
    }
    __syncthreads();

    // ---------- epilogue: weighted per-thread accumulator ----------
    float s = 0.0f;

    // cls BCE for this block's 5 targets: threads 0..399, one (t,c) each
    if (tid < TPG * NC) {
        const int t = tid / NC;
        const int c = tid - t * NC;
        float x = pcls[((size_t)b * NA + sbi5[t]) * NC + c];
        int lab = tl[b * NT + g * TPG + t];
        s += W_CLS * (bce0(x) - (lab == c ? x : 0.0f));
    }

    // CIoU for this block's 5 targets (threads 512..516, exact reference formula)
    if (tid >= 512 && tid < 512 + TPG) {
        const int t  = tid - 512;
        const int bi = sbi5[t];
        const float* p  = pb + ((size_t)b * NA + bi) * 4;
        const float* tg = tb + ((size_t)b * NT + g * TPG + t) * 4;
        float b1x1 = p[0],  b1y1 = p[1],  b1x2 = p[2],  b1y2 = p[3];
        float b2x1 = tg[0], b2y1 = tg[1], b2x2 = tg[2], b2y2 = tg[3];

        float area1 = (b1x2 - b1x1) * (b1y2 - b1y1);
        float area2 = (b2x2 - b2x1) * (b2y2 - b2y1);
        float iw = fmaxf(fminf(b1x2, b2x2) - fmaxf(b1x1, b2x1), 0.0f);
        float ih = fmaxf(fminf(b1y2, b2y2) - fmaxf(b1y1, b2y1), 0.0f);
        float inter = iw * ih;
        float iou = inter / (area1 + area2 - inter + F_EPS);

        float cdx = fmaxf(b1x2, b2x2) - fminf(b1x1, b2x1);
        float cdy = fmaxf(b1y2, b2y2) - fminf(b1y1, b2y1);
        float c_diag = cdx * cdx + cdy * cdy;

        float cx = (b1x1 + b1x2 - b2x1 - b2x2) * 0.5f;
        float cy = (b1y1 + b1y2 - b2y1 - b2y2) * 0.5f;
        float center_dist = cx * cx + cy * cy;

        float w1 = b1x2 - b1x1, h1 = b1y2 - b1y1;
        float w2 = b2x2 - b2x1, h2 = b2y2 - b2y1;
        float dat = atanf(w2 / h2) - atanf(w1 / h1);
        float vv = (float)(4.0 / (M_PI * M_PI)) * dat * dat;
        float alpha = vv / (1.0f - iou + vv + F_EPS);
        float ciou = iou - center_dist / c_diag - alpha * vv;
        s += W_BOX * (1.0f - ciou);
    }

    // bulk objectness: this block's 480-float4 slice of pc (no mask needed)
    if (tid < OBJ_F4_PER_BLK) {
        float4 v4 = pc4[blockIdx.x * OBJ_F4_PER_BLK + tid];
        s += W_OBJ * (bce0(v4.x) + bce0(v4.y) + bce0(v4.z) + bce0(v4.w));
    }

    // block reduce -> part[blockIdx.x]
    #pragma unroll
    for (int m = 32; m > 0; m >>= 1) s += __shfl_down(s, m);
    if (lane == 0) swred[wave] = s;
    __syncthreads();
    if (tid < KA_WAVES) {
        float v = swred[tid];
        #pragma unroll
        for (int m = 8; m > 0; m >>= 1) v += __shfl_down(v, m);
        if (tid == 0) part[blockIdx.x] = v;
    }
}

// ---- Node B: sum partials + dedup'd objectness correction (1 block) ----
__global__ __launch_bounds__(256) void kB(
        const float* __restrict__ pc,
        const int* __restrict__ best_idx,
        const float* __restrict__ part,
        float* __restrict__ out) {
    const int tid = threadIdx.x;
    const int wave = tid >> 6;
    const int lane = tid & 63;

    __shared__ int   sbi[NB * NT];
    __shared__ float swred[4];

    for (int i = tid; i < NB * NT; i += 256) sbi[i] = best_idx[i];
    __syncthreads();

    float s = 0.0f;
    if (tid < KA_BLOCKS) s += part[tid];

    // obj correction: bce(x,1)-bce(x,0) = -x, once per UNIQUE best anchor per image
    for (int i = tid; i < NB * NT; i += 256) {
        const int b = i / NT;
        const int t = i - b * NT;
        const int bi = sbi[i];
        bool dup = false;
        for (int tp = 0; tp < t; ++tp)
            if (sbi[b * NT + tp] == bi) dup = true;
        if (!dup) s -= W_OBJ * pc[(size_t)b * NA + bi];
    }

    #pragma unroll
    for (int m = 32; m > 0; m >>= 1) s += __shfl_down(s, m);
    if (lane == 0) swred[wave] = s;
    __syncthreads();
    if (tid == 0) out[0] = swred[0] + swred[1] + swred[2] + swred[3];
}

extern "C" void kernel_launch(void* const* d_in, const int* in_sizes, int n_in,
                              void* d_out, int out_size, void* d_ws, size_t ws_size,
                              hipStream_t stream) {
    const float* pb   = (const float*)d_in[0];   // (B,A,4)
    const float* pc   = (const float*)d_in[1];   // (B,A,1)
    const float* pcls = (const float*)d_in[2];   // (B,A,C)
    const float* tb   = (const float*)d_in[3];   // (B,T,4)
    const int*   tl   = (const int*)d_in[4];     // (B,T)

    char* ws = (char*)d_ws;
    float* part     = (float*)ws;             // 160 floats
    int*   best_idx = (int*)(ws + 1024);      // 800 ints

    kA<<<KA_BLOCKS, KA_THREADS, 0, stream>>>(pb, pc, pcls, tb, tl, best_idx, part);
    kB<<<1, 256, 0, stream>>>(pc, best_idx, part, (float*)d_out);
}